// Round 7
// baseline (122.701 us; speedup 1.0000x reference)
//
#include <hip/hip_runtime.h>
#include <stdint.h>

#define NAG 4096
#define TOPK 12
#define EPSF 1e-4f
#define NT 256
#define WPB 4               // waves (=agents) per block
#define MTOT (NAG * TOPK)   // 49152 rows

typedef unsigned long long u64;
typedef short short8v __attribute__((ext_vector_type(8)));
typedef float f32x4 __attribute__((ext_vector_type(4)));

__device__ __forceinline__ u64 umin64(u64 a, u64 b) { return a < b ? a : b; }

// round-to-nearest-even f32 -> bf16 bits
__device__ __forceinline__ unsigned short f2bf(float f) {
    union { float f; unsigned u; } v; v.f = f;
    unsigned r = v.u + 0x7FFFu + ((v.u >> 16) & 1u);
    return (unsigned short)(r >> 16);
}

// One DPP stage of a 64-lane (hi,lo) u64-min reduction. old=self so lanes
// without a valid source are identity under min. (Validated R5/R6: selection
// bit-identical to LDS-shuffle version.)
template <int CTRL>
__device__ __forceinline__ void dpp_min_step(unsigned &hi, unsigned &lo) {
    unsigned ohi = (unsigned)__builtin_amdgcn_update_dpp((int)hi, (int)hi, CTRL, 0xf, 0xf, false);
    unsigned olo = (unsigned)__builtin_amdgcn_update_dpp((int)lo, (int)lo, CTRL, 0xf, 0xf, false);
    bool t = (ohi < hi) || (ohi == hi && olo < lo);
    hi = t ? ohi : hi;
    lo = t ? olo : lo;
}

// ============ Kernel 1: wave-per-agent top-12 + SCRAMBLED x rows ============
// ZERO __syncthreads: each wave handles one agent end-to-end.
// Selection: T = 12th-smallest of 64 lane-min keys (provable upper bound on
// true d12: 12 distinct lanes own candidates <= T). Ballot-compact survivors
// (E[cnt] ~ 13), exact u64-key rank-select (key order == lax.top_k order).
__global__ __launch_bounds__(NT, 4)
void cbf_select(const float* __restrict__ states,
                float* __restrict__ xbuf,   // [MTOT][8] f32 (scrambled channel vecs)
                float* __restrict__ out)    // mask -> out[MTOT + m]
{
    const int t = threadIdx.x;
    const int lane = t & 63;
    const int wv = t >> 6;
    const int i = blockIdx.x * WPB + wv;    // agent

    __shared__ u64 s_surv[WPB][64];
    __shared__ int s_sel[WPB][TOPK];
    __shared__ float s_x[WPB][72];          // flat72: slot-major, 6 feats

    const float2* st2 = reinterpret_cast<const float2*>(states);
    const float si0 = states[i * 4 + 0];
    const float si1 = states[i * 4 + 1];

    // ---- Phase 1: 64 candidates/lane, dn bits in REGISTERS (static indexing)
    unsigned dnb[64];
    unsigned minb = 0xFFFFFFFFu;
    int minj = 0;
#pragma unroll
    for (int u = 0; u < 64; ++u) {
        int j = u * 64 + lane;
        float2 sj = st2[j * 2];              // states[j][0..1]
        float dx0 = __fsub_rn(si0, sj.x);
        float dx1 = __fsub_rn(si1, sj.y);
        float d2 = __fadd_rn(__fadd_rn(__fmul_rn(dx0, dx0), EPSF),
                             __fadd_rn(__fmul_rn(dx1, dx1), EPSF));
        unsigned b = __float_as_uint(__fsqrt_rn(d2));   // positive: bit order == value order
        dnb[u] = b;
        if (b < minb) { minb = b; minj = j; }  // strict <: lowest j wins ties (u asc = j asc)
    }

    // ---- Phase 2: T = 12th-smallest lane-min key (12 static DPP rounds, in-wave)
    unsigned Tb;
    {
        unsigned khi = minb, klo = (unsigned)minj;
        unsigned Tcur = 0;
        for (int r = 0; r < TOPK; ++r) {
            unsigned hi = khi, lo = klo;
            dpp_min_step<0xB1>(hi, lo);    // quad_perm xor1
            dpp_min_step<0x4E>(hi, lo);    // quad_perm xor2
            dpp_min_step<0x124>(hi, lo);   // row_ror:4
            dpp_min_step<0x128>(hi, lo);   // row_ror:8
            dpp_min_step<0x142>(hi, lo);   // row_bcast15
            dpp_min_step<0x143>(hi, lo);   // row_bcast31
            unsigned hw = (unsigned)__builtin_amdgcn_readlane((int)hi, 63);
            unsigned lw = (unsigned)__builtin_amdgcn_readlane((int)lo, 63);
            Tcur = hw;
            // mask winner (klo=j unique -> exactly one lane)
            if (khi == hw && klo == lw) khi = 0xFFFFFFFFu;
        }
        Tb = Tcur;
    }

    // ---- Phase 3: ballot-compact survivors (dnb <= Tb); >=12 guaranteed
    int cnt = 0;
#pragma unroll
    for (int u = 0; u < 64; ++u) {
        bool p = (dnb[u] <= Tb);
        u64 mk = __ballot(p);
        if (p) {
            int pos = cnt + __popcll(mk & ((1ull << lane) - 1ull));
            if (pos < 64)
                s_surv[wv][pos] = ((u64)dnb[u] << 32) | (unsigned)(u * 64 + lane);
        }
        cnt += __popcll(mk);
    }
    if (cnt > 64) cnt = 64;
    __asm volatile("s_waitcnt lgkmcnt(0)" ::: "memory");
    __builtin_amdgcn_wave_barrier();

    // ---- Phase 4: exact rank-select over survivors (key order == lax.top_k)
    if (lane < cnt) {
        u64 kA = s_surv[wv][lane];
        int rA = 0;
        for (int q = 0; q < cnt; ++q)
            rA += (s_surv[wv][q] < kA) ? 1 : 0;   // uniform addr -> broadcast
        if (rA < TOPK) s_sel[wv][rA] = (int)(unsigned)(kA & 0xffffffffull);
    }
    __asm volatile("s_waitcnt lgkmcnt(0)" ::: "memory");
    __builtin_amdgcn_wave_barrier();

    // ---- Phase 5a: build flat72 + mask
    if (lane < TOPK) {
        int j = s_sel[wv][lane];
        const float4 sj = reinterpret_cast<const float4*>(states)[j];
        const float4 si = reinterpret_cast<const float4*>(states)[i];
        float dx0 = __fsub_rn(si.x, sj.x);
        float dx1 = __fsub_rn(si.y, sj.y);
        float dx2 = __fsub_rn(si.z, sj.z);
        float dx3 = __fsub_rn(si.w, sj.w);
        float d2 = __fadd_rn(__fadd_rn(__fmul_rn(dx0, dx0), EPSF),
                             __fadd_rn(__fmul_rn(dx1, dx1), EPSF));
        float dn = __fsqrt_rn(d2);
        s_x[wv][lane * 6 + 0] = dx0;
        s_x[wv][lane * 6 + 1] = dx1;
        s_x[wv][lane * 6 + 2] = dx2;
        s_x[wv][lane * 6 + 3] = dx3;
        s_x[wv][lane * 6 + 4] = (j == i) ? 1.0f : 0.0f;
        s_x[wv][lane * 6 + 5] = __fsub_rn(dn, 0.8f);
        out[MTOT + i * TOPK + lane] = (dn <= 1.0f) ? 1.0f : 0.0f;
    }
    __asm volatile("s_waitcnt lgkmcnt(0)" ::: "memory");
    __builtin_amdgcn_wave_barrier();

    // ---- Phase 5b: scrambled channel vectors: xbuf[m][ch] = flat72[ch*12+lane]
    if (lane < TOPK) {
        int m = i * TOPK + lane;
        float4 v0 = {s_x[wv][0 * 12 + lane], s_x[wv][1 * 12 + lane],
                     s_x[wv][2 * 12 + lane], s_x[wv][3 * 12 + lane]};
        float4 v1 = {s_x[wv][4 * 12 + lane], s_x[wv][5 * 12 + lane], 0.0f, 0.0f};
        reinterpret_cast<float4*>(xbuf + m * 8)[0] = v0;
        reinterpret_cast<float4*>(xbuf + m * 8)[1] = v1;
    }
}

// ============ Kernel 2: batched MLP (L1 f32, L2/L3 MFMA bf16, L4 f32) ============
// 768 blocks x 256 threads; wave owns a 16-row M-tile. (unchanged from R6)
__global__ __launch_bounds__(256)
void cbf_mlp(const float* __restrict__ xbuf,
             const float* __restrict__ W1, const float* __restrict__ b1,
             const float* __restrict__ W2, const float* __restrict__ b2,
             const float* __restrict__ W3, const float* __restrict__ b3,
             const float* __restrict__ W4, const float* __restrict__ b4,
             float* __restrict__ out)
{
    const int t = threadIdx.x;
    const int lane = t & 63;
    const int wv = t >> 6;
    const int r16 = lane & 15;      // row within 16-tile / D column
    const int hi = lane >> 4;       // 0..3
    const int m0 = blockIdx.x * 64 + wv * 16;

    __shared__ __align__(16) unsigned char s_h1[4 * 2048];   // [wave][16 rows][64 bf16]
    __shared__ __align__(16) unsigned char s_h2[4 * 4096];   // [wave][16 rows][128 bf16]
    unsigned char* lp1 = s_h1 + wv * 2048;
    unsigned char* lp2 = s_h2 + wv * 4096;

    // ---- L1 (f32): lane computes h1[row=r16][o = hi*16 .. hi*16+15]
    const int mrow = m0 + r16;
    const float4 xa = reinterpret_cast<const float4*>(xbuf + mrow * 8)[0];
    const float4 xb = reinterpret_cast<const float4*>(xbuf + mrow * 8)[1];
    const float xc[6] = {xa.x, xa.y, xa.z, xa.w, xb.x, xb.y};

    unsigned short h1b[16];
#pragma unroll
    for (int ol = 0; ol < 16; ++ol) {
        int o = hi * 16 + ol;
        const float2* wr = reinterpret_cast<const float2*>(W1 + o * 6);
        float2 w0 = wr[0], w1 = wr[1], w2 = wr[2];
        float acc = b1[o];
        acc = fmaf(w0.x, xc[0], acc);
        acc = fmaf(w0.y, xc[1], acc);
        acc = fmaf(w1.x, xc[2], acc);
        acc = fmaf(w1.y, xc[3], acc);
        acc = fmaf(w2.x, xc[4], acc);
        acc = fmaf(w2.y, xc[5], acc);
        h1b[ol] = f2bf(fmaxf(acc, 0.0f));
    }
    // stage h1 -> LDS (bf16, XOR-swizzled 16B slots: slot' = slot ^ (row&7))
    {
        short8v p0, p1;
#pragma unroll
        for (int e = 0; e < 8; ++e) { p0[e] = (short)h1b[e]; p1[e] = (short)h1b[8 + e]; }
        int rowb = r16 * 128;
        *(short8v*)(lp1 + rowb + (((2 * hi + 0) ^ (r16 & 7)) * 16)) = p0;
        *(short8v*)(lp1 + rowb + (((2 * hi + 1) ^ (r16 & 7)) * 16)) = p1;
    }
    __syncthreads();

    // ---- L2 (MFMA): A-frags from LDS; h2 = relu(h1 @ W2^T + b2), 128 cols
    short8v a0 = *(short8v*)(lp1 + r16 * 128 + (((0 + hi) ^ (r16 & 7)) * 16));  // ks=0
    short8v a1 = *(short8v*)(lp1 + r16 * 128 + (((4 + hi) ^ (r16 & 7)) * 16));  // ks=1
    const int c = r16;   // D/B column within tile
#pragma unroll
    for (int nt = 0; nt < 8; ++nt) {
        const float* wrow = W2 + (nt * 16 + c) * 64;
        float4 g0 = *(const float4*)(wrow + 8 * hi);
        float4 g1 = *(const float4*)(wrow + 8 * hi + 4);
        float4 g2 = *(const float4*)(wrow + 32 + 8 * hi);
        float4 g3 = *(const float4*)(wrow + 36 + 8 * hi);
        short8v bf0, bf1;
        bf0[0] = (short)f2bf(g0.x); bf0[1] = (short)f2bf(g0.y);
        bf0[2] = (short)f2bf(g0.z); bf0[3] = (short)f2bf(g0.w);
        bf0[4] = (short)f2bf(g1.x); bf0[5] = (short)f2bf(g1.y);
        bf0[6] = (short)f2bf(g1.z); bf0[7] = (short)f2bf(g1.w);
        bf1[0] = (short)f2bf(g2.x); bf1[1] = (short)f2bf(g2.y);
        bf1[2] = (short)f2bf(g2.z); bf1[3] = (short)f2bf(g2.w);
        bf1[4] = (short)f2bf(g3.x); bf1[5] = (short)f2bf(g3.y);
        bf1[6] = (short)f2bf(g3.z); bf1[7] = (short)f2bf(g3.w);
        float bb = b2[nt * 16 + c];
        f32x4 acc = {bb, bb, bb, bb};
        acc = __builtin_amdgcn_mfma_f32_16x16x32_bf16(a0, bf0, acc, 0, 0, 0);
        acc = __builtin_amdgcn_mfma_f32_16x16x32_bf16(a1, bf1, acc, 0, 0, 0);
#pragma unroll
        for (int e = 0; e < 4; ++e) {
            unsigned short hv = f2bf(fmaxf(acc[e], 0.0f));
            int mr = 4 * hi + e;                    // D row
            int slot = (2 * nt + (c >> 3)) ^ (mr & 15);
            *(unsigned short*)(lp2 + mr * 256 + slot * 16 + ((2 * c) & 15)) = hv;
        }
    }
    __syncthreads();

    // ---- L3 (MFMA): h3 = relu(h2 @ W3^T + b3), 64 cols
    short8v a3[4];
#pragma unroll
    for (int ks = 0; ks < 4; ++ks)
        a3[ks] = *(short8v*)(lp2 + r16 * 256 + (((4 * ks + hi) ^ r16) * 16));
    float h3r[4][4];
#pragma unroll
    for (int nt = 0; nt < 4; ++nt) {
        const float* wrow = W3 + (nt * 16 + c) * 128;
        float bb = b3[nt * 16 + c];
        f32x4 ac = {bb, bb, bb, bb};
#pragma unroll
        for (int ks = 0; ks < 4; ++ks) {
            float4 q0 = *(const float4*)(wrow + ks * 32 + 8 * hi);
            float4 q1 = *(const float4*)(wrow + ks * 32 + 8 * hi + 4);
            short8v bf;
            bf[0] = (short)f2bf(q0.x); bf[1] = (short)f2bf(q0.y);
            bf[2] = (short)f2bf(q0.z); bf[3] = (short)f2bf(q0.w);
            bf[4] = (short)f2bf(q1.x); bf[5] = (short)f2bf(q1.y);
            bf[6] = (short)f2bf(q1.z); bf[7] = (short)f2bf(q1.w);
            ac = __builtin_amdgcn_mfma_f32_16x16x32_bf16(a3[ks], bf, ac, 0, 0, 0);
        }
#pragma unroll
        for (int e = 0; e < 4; ++e) h3r[nt][e] = fmaxf(ac[e], 0.0f);
    }

    // ---- L4 (f32): out[m] = (h3 . W4 + b4) * mask; reduce over 16 lanes
    float w4c[4];
#pragma unroll
    for (int nt = 0; nt < 4; ++nt) w4c[nt] = W4[nt * 16 + c];
    float part[4];
#pragma unroll
    for (int e = 0; e < 4; ++e) {
        float p = h3r[0][e] * w4c[0];
        p = fmaf(h3r[1][e], w4c[1], p);
        p = fmaf(h3r[2][e], w4c[2], p);
        p = fmaf(h3r[3][e], w4c[3], p);
        part[e] = p;
    }
#pragma unroll
    for (int off = 1; off <= 8; off <<= 1) {
#pragma unroll
        for (int e = 0; e < 4; ++e)
            part[e] += __shfl_xor(part[e], off, 64);
    }
    if (c == 0) {
        float bb4 = b4[0];
#pragma unroll
        for (int e = 0; e < 4; ++e) {
            int m = m0 + 4 * hi + e;
            float mk = out[MTOT + m];
            out[m] = (part[e] + bb4) * mk;
        }
    }
}

extern "C" void kernel_launch(void* const* d_in, const int* in_sizes, int n_in,
                              void* d_out, int out_size, void* d_ws, size_t ws_size,
                              hipStream_t stream) {
    const float* states = (const float*)d_in[0];
    const float* W1 = (const float*)d_in[1];
    const float* b1 = (const float*)d_in[2];
    const float* W2 = (const float*)d_in[3];
    const float* b2 = (const float*)d_in[4];
    const float* W3 = (const float*)d_in[5];
    const float* b3 = (const float*)d_in[6];
    const float* W4 = (const float*)d_in[7];
    const float* b4 = (const float*)d_in[8];
    float* out = (float*)d_out;
    float* xbuf = (float*)d_ws;   // MTOT*8 f32 = 1.57 MB

    cbf_select<<<dim3(NAG / WPB), dim3(NT), 0, stream>>>(states, xbuf, out);
    cbf_mlp<<<dim3(MTOT / 64), dim3(256), 0, stream>>>(xbuf, W1, b1, W2, b2,
                                                       W3, b3, W4, b4, out);
}

// Round 11
// 102.625 us; speedup vs baseline: 1.1956x; 1.1956x over previous
//
#include <hip/hip_runtime.h>
#include <stdint.h>

#define NAG 4096
#define TOPK 12
#define EPSF 1e-4f
#define NT 256
#define PT (NAG / NT)       // 16 candidates per thread
#define MTOT (NAG * TOPK)   // 49152 rows

typedef unsigned long long u64;
typedef short short8v __attribute__((ext_vector_type(8)));
typedef float f32x4 __attribute__((ext_vector_type(4)));

__device__ __forceinline__ u64 umin64(u64 a, u64 b) { return a < b ? a : b; }

// round-to-nearest-even f32 -> bf16 bits
__device__ __forceinline__ unsigned short f2bf(float f) {
    union { float f; unsigned u; } v; v.f = f;
    unsigned r = v.u + 0x7FFFu + ((v.u >> 16) & 1u);
    return (unsigned short)(r >> 16);
}

// One DPP stage of a 64-lane (hi,lo) u64-min reduction (validated R5-R7).
template <int CTRL>
__device__ __forceinline__ void dpp_min_step(unsigned &hi, unsigned &lo) {
    unsigned ohi = (unsigned)__builtin_amdgcn_update_dpp((int)hi, (int)hi, CTRL, 0xf, 0xf, false);
    unsigned olo = (unsigned)__builtin_amdgcn_update_dpp((int)lo, (int)lo, CTRL, 0xf, 0xf, false);
    bool t = (ohi < hi) || (ohi == hi && olo < lo);
    hi = t ? ohi : hi;
    lo = t ? olo : lo;
}

// ======= Kernel 0: preconvert W2,W3 -> bf16 (Wb[0:8192]=W2, Wb[8192:16384]=W3)
__global__ __launch_bounds__(256)
void cbf_prep(const float* __restrict__ W2, const float* __restrict__ W3,
              unsigned short* __restrict__ Wb) {
    int t = threadIdx.x;
#pragma unroll
    for (int k = 0; k < 64; ++k) {
        int idx = k * 256 + t;
        float v = (idx < 8192) ? W2[idx] : W3[idx - 8192];
        Wb[idx] = f2bf(v);
    }
}

// ======= Kernel 1: FUSED select + per-agent MFMA MLP (one block per agent) ====
// Select = R6's threshold-compaction (fastest variant so far, unchanged).
// MLP = wave 0 only, one 16-row MFMA tile (12 valid rows), K2's validated
// fragment layouts verbatim; weights preconverted bf16.
__global__ __launch_bounds__(NT, 4)
void cbf_fused(const float* __restrict__ states,
               const float* __restrict__ W1, const float* __restrict__ b1,
               const unsigned short* __restrict__ Wb,   // W2bf | W3bf
               const float* __restrict__ b2, const float* __restrict__ b3,
               const float* __restrict__ W4, const float* __restrict__ b4,
               float* __restrict__ out)
{
    const int i = blockIdx.x;
    const int t = threadIdx.x;
    const int lane = t & 63;
    const int wv = t >> 6;

    __shared__ u64 s_min[NT];        // per-thread min key (dnbits<<32 | j)
    __shared__ u64 s_surv[64];       // survivor keys
    __shared__ int s_sel[TOPK];
    __shared__ float s_x[72];        // flat72: slot-major, 6 feats
    __shared__ float s_mask[TOPK];
    __shared__ unsigned s_cnt;
    __shared__ unsigned s_T;
    __shared__ __align__(16) unsigned char s_h1[2048];   // [16 rows][64 bf16]
    __shared__ __align__(16) unsigned char s_h2[4096];   // [16 rows][128 bf16]

    if (t == 0) s_cnt = 0;

    const float2* st2 = reinterpret_cast<const float2*>(states);
    const float si0 = states[i * 4 + 0];
    const float si1 = states[i * 4 + 1];

    // ---- Phase 1: distances in registers (bit-exact f32: no contraction, rn sqrt)
    unsigned dnb[PT];
    float mind = 1e30f;
    int minu = 0;
#pragma unroll
    for (int u = 0; u < PT; ++u) {
        int j = u * NT + t;
        float2 sj = st2[j * 2];
        float dx0 = __fsub_rn(si0, sj.x);
        float dx1 = __fsub_rn(si1, sj.y);
        float d2 = __fadd_rn(__fadd_rn(__fmul_rn(dx0, dx0), EPSF),
                             __fadd_rn(__fmul_rn(dx1, dx1), EPSF));
        float dn = __fsqrt_rn(d2);
        dnb[u] = __float_as_uint(dn);
        if (dn < mind) { mind = dn; minu = u; }  // strict <: lower u (=lower j) wins ties
    }
    s_min[t] = ((u64)__float_as_uint(mind) << 32) | (unsigned)(minu * NT + t);
    __syncthreads();

    // ---- Phase 2: wave 0 finds T = 12th-smallest per-thread-min (static DPP)
    if (wv == 0) {
        unsigned khi[4], klo[4];
#pragma unroll
        for (int q = 0; q < 4; ++q) {
            u64 kk = s_min[lane + q * 64];
            klo[q] = (unsigned)(kk & 0xffffffffull);
            khi[q] = (unsigned)(kk >> 32);
        }
        unsigned Tb = 0;
        for (int r = 0; r < TOPK; ++r) {
            unsigned hi = khi[0], lo = klo[0];
#pragma unroll
            for (int q = 1; q < 4; ++q) {
                bool tk = (khi[q] < hi) || (khi[q] == hi && klo[q] < lo);
                hi = tk ? khi[q] : hi;
                lo = tk ? klo[q] : lo;
            }
            dpp_min_step<0xB1>(hi, lo);
            dpp_min_step<0x4E>(hi, lo);
            dpp_min_step<0x124>(hi, lo);
            dpp_min_step<0x128>(hi, lo);
            dpp_min_step<0x142>(hi, lo);
            dpp_min_step<0x143>(hi, lo);
            unsigned hw = (unsigned)__builtin_amdgcn_readlane((int)hi, 63);
            unsigned lw = (unsigned)__builtin_amdgcn_readlane((int)lo, 63);
            Tb = hw;
#pragma unroll
            for (int q = 0; q < 4; ++q) {
                bool w = (khi[q] == hw) && (klo[q] == lw);
                khi[q] = w ? 0xFFFFFFFFu : khi[q];
            }
        }
        if (lane == 0) s_T = Tb;
    }
    __syncthreads();

    // ---- Phase 3: compact survivors (dn <= T); >=12 guaranteed, ~13 typical
    {
        unsigned Tb = s_T;
#pragma unroll
        for (int u = 0; u < PT; ++u) {
            if (dnb[u] <= Tb) {
                unsigned slot = atomicAdd(&s_cnt, 1u);
                if (slot < 64)
                    s_surv[slot] = ((u64)dnb[u] << 32) | (unsigned)(u * NT + t);
            }
        }
    }
    __syncthreads();

    // ================= everything below is WAVE 0 ONLY =================
    if (wv != 0) return;

    // ---- Phase 4: exact rank-select (key order == lax.top_k order)
    {
        int cnt = (int)s_cnt;
        if (cnt > 64) cnt = 64;
        u64 kA = (lane < cnt) ? s_surv[lane] : ~0ull;
        int rA = 0;
        for (int q = 0; q < cnt; ++q)
            rA += (s_surv[q] < kA) ? 1 : 0;
        if (lane < cnt && rA < TOPK) s_sel[rA] = (int)(unsigned)(kA & 0xffffffffull);
    }
    __asm volatile("s_waitcnt lgkmcnt(0)" ::: "memory");
    __builtin_amdgcn_wave_barrier();

    // ---- Phase 5: build flat72 + mask
    if (lane < TOPK) {
        int j = s_sel[lane];
        const float4 sj = reinterpret_cast<const float4*>(states)[j];
        const float4 si = reinterpret_cast<const float4*>(states)[i];
        float dx0 = __fsub_rn(si.x, sj.x);
        float dx1 = __fsub_rn(si.y, sj.y);
        float dx2 = __fsub_rn(si.z, sj.z);
        float dx3 = __fsub_rn(si.w, sj.w);
        float d2 = __fadd_rn(__fadd_rn(__fmul_rn(dx0, dx0), EPSF),
                             __fadd_rn(__fmul_rn(dx1, dx1), EPSF));
        float dn = __fsqrt_rn(d2);
        s_x[lane * 6 + 0] = dx0;
        s_x[lane * 6 + 1] = dx1;
        s_x[lane * 6 + 2] = dx2;
        s_x[lane * 6 + 3] = dx3;
        s_x[lane * 6 + 4] = (j == i) ? 1.0f : 0.0f;
        s_x[lane * 6 + 5] = __fsub_rn(dn, 0.8f);
        float mk = (dn <= 1.0f) ? 1.0f : 0.0f;
        s_mask[lane] = mk;
        out[MTOT + i * TOPK + lane] = mk;
    }
    __asm volatile("s_waitcnt lgkmcnt(0)" ::: "memory");
    __builtin_amdgcn_wave_barrier();

    // ---- MLP (wave 0, one 16-row tile; rows 12..15 zero-padded) ----
    const int r16 = lane & 15;      // M row / D col index
    const int hi = lane >> 4;       // 0..3

    // L1 (f32): scrambled input: xc[ch] = flat72[ch*12 + r16]
    float xc[6];
#pragma unroll
    for (int ch = 0; ch < 6; ++ch)
        xc[ch] = (r16 < TOPK) ? s_x[ch * TOPK + r16] : 0.0f;

    unsigned short h1b[16];
#pragma unroll
    for (int ol = 0; ol < 16; ++ol) {
        int o = hi * 16 + ol;
        const float2* wr = reinterpret_cast<const float2*>(W1 + o * 6);
        float2 w0 = wr[0], w1 = wr[1], w2 = wr[2];
        float acc = b1[o];
        acc = fmaf(w0.x, xc[0], acc);
        acc = fmaf(w0.y, xc[1], acc);
        acc = fmaf(w1.x, xc[2], acc);
        acc = fmaf(w1.y, xc[3], acc);
        acc = fmaf(w2.x, xc[4], acc);
        acc = fmaf(w2.y, xc[5], acc);
        h1b[ol] = (r16 < TOPK) ? f2bf(fmaxf(acc, 0.0f)) : (unsigned short)0;
    }
    // stage h1 -> LDS (bf16, XOR-swizzled 16B slots: slot' = slot ^ (row&7))
    {
        short8v p0, p1;
#pragma unroll
        for (int e = 0; e < 8; ++e) { p0[e] = (short)h1b[e]; p1[e] = (short)h1b[8 + e]; }
        int rowb = r16 * 128;
        *(short8v*)(s_h1 + rowb + (((2 * hi + 0) ^ (r16 & 7)) * 16)) = p0;
        *(short8v*)(s_h1 + rowb + (((2 * hi + 1) ^ (r16 & 7)) * 16)) = p1;
    }
    __asm volatile("s_waitcnt lgkmcnt(0)" ::: "memory");
    __builtin_amdgcn_wave_barrier();

    // L2 (MFMA): h2 = relu(h1 @ W2^T + b2), 128 cols; W2bf = Wb[0:8192]
    short8v a0 = *(short8v*)(s_h1 + r16 * 128 + (((0 + hi) ^ (r16 & 7)) * 16));
    short8v a1 = *(short8v*)(s_h1 + r16 * 128 + (((4 + hi) ^ (r16 & 7)) * 16));
    const int c = r16;
#pragma unroll
    for (int nt = 0; nt < 8; ++nt) {
        int o = nt * 16 + c;
        short8v bf0 = *(const short8v*)(Wb + o * 64 + 8 * hi);
        short8v bf1 = *(const short8v*)(Wb + o * 64 + 32 + 8 * hi);
        float bb = b2[o];
        f32x4 acc = {bb, bb, bb, bb};
        acc = __builtin_amdgcn_mfma_f32_16x16x32_bf16(a0, bf0, acc, 0, 0, 0);
        acc = __builtin_amdgcn_mfma_f32_16x16x32_bf16(a1, bf1, acc, 0, 0, 0);
#pragma unroll
        for (int e = 0; e < 4; ++e) {
            unsigned short hv = f2bf(fmaxf(acc[e], 0.0f));
            int mr = 4 * hi + e;
            int slot = (2 * nt + (c >> 3)) ^ (mr & 15);
            *(unsigned short*)(s_h2 + mr * 256 + slot * 16 + ((2 * c) & 15)) = hv;
        }
    }
    __asm volatile("s_waitcnt lgkmcnt(0)" ::: "memory");
    __builtin_amdgcn_wave_barrier();

    // L3 (MFMA): h3 = relu(h2 @ W3^T + b3), 64 cols; W3bf = Wb[8192:]
    short8v a3[4];
#pragma unroll
    for (int ks = 0; ks < 4; ++ks)
        a3[ks] = *(short8v*)(s_h2 + r16 * 256 + (((4 * ks + hi) ^ r16) * 16));
    float h3r[4][4];
#pragma unroll
    for (int nt = 0; nt < 4; ++nt) {
        int o = nt * 16 + c;
        float bb = b3[o];
        f32x4 ac = {bb, bb, bb, bb};
#pragma unroll
        for (int ks = 0; ks < 4; ++ks) {
            short8v bf = *(const short8v*)(Wb + 8192 + o * 128 + ks * 32 + 8 * hi);
            ac = __builtin_amdgcn_mfma_f32_16x16x32_bf16(a3[ks], bf, ac, 0, 0, 0);
        }
#pragma unroll
        for (int e = 0; e < 4; ++e) h3r[nt][e] = fmaxf(ac[e], 0.0f);
    }

    // L4 (f32): out[m] = (h3 . W4 + b4) * mask; reduce over the 16 c-lanes
    float w4c[4];
#pragma unroll
    for (int nt = 0; nt < 4; ++nt) w4c[nt] = W4[nt * 16 + c];
    float part[4];
#pragma unroll
    for (int e = 0; e < 4; ++e) {
        float p = h3r[0][e] * w4c[0];
        p = fmaf(h3r[1][e], w4c[1], p);
        p = fmaf(h3r[2][e], w4c[2], p);
        p = fmaf(h3r[3][e], w4c[3], p);
        part[e] = p;
    }
#pragma unroll
    for (int off = 1; off <= 8; off <<= 1) {
#pragma unroll
        for (int e = 0; e < 4; ++e)
            part[e] += __shfl_xor(part[e], off, 64);
    }
    if (c == 0) {
        float bb4 = b4[0];
#pragma unroll
        for (int e = 0; e < 4; ++e) {
            int mr = 4 * hi + e;
            if (mr < TOPK)
                out[i * TOPK + mr] = (part[e] + bb4) * s_mask[mr];
        }
    }
}

extern "C" void kernel_launch(void* const* d_in, const int* in_sizes, int n_in,
                              void* d_out, int out_size, void* d_ws, size_t ws_size,
                              hipStream_t stream) {
    const float* states = (const float*)d_in[0];
    const float* W1 = (const float*)d_in[1];
    const float* b1 = (const float*)d_in[2];
    const float* W2 = (const float*)d_in[3];
    const float* b2 = (const float*)d_in[4];
    const float* W3 = (const float*)d_in[5];
    const float* b3 = (const float*)d_in[6];
    const float* W4 = (const float*)d_in[7];
    const float* b4 = (const float*)d_in[8];
    float* out = (float*)d_out;
    unsigned short* Wb = (unsigned short*)d_ws;   // 16384 bf16 = 32 KB

    cbf_prep<<<dim3(1), dim3(256), 0, stream>>>(W2, W3, Wb);
    cbf_fused<<<dim3(NAG), dim3(NT), 0, stream>>>(states, W1, b1, Wb,
                                                  b2, b3, W4, b4, out);
}